// Round 21
// baseline (304.803 us; speedup 1.0000x reference)
//
#include <hip/hip_runtime.h>

#define NN 50000
#define EE 800000
#define DD 64
#define NL 3
#define UIN 832
#define XW 256   // stored x row: [mean | mx | mn | sd] (h read directly from g_hb)
#define DELTA_F 2.833213344056216f
#define SLOPE 0.01f
#define SCAN_BLKS 196  // 196*256 = 50176 >= NN
#define UPD_BLKS 1024
#define NTILE 3125     // NN/16
#define NCPY 8         // histogram replicas (~one per XCD)
#define SGRP 8         // scatter position-range groups
#define SCAT_BLKS 3128 // 391 blocks per group

typedef __attribute__((ext_vector_type(8))) short short8;
typedef __attribute__((ext_vector_type(4))) float floatx4;

// ---- static device buffers (fully rewritten every call) ----
__device__ __align__(16) unsigned short g_hb[2][NN * DD];       // bf16 h (double buffer)
__device__ __align__(16) unsigned short g_p1[NN * DD];          // M1 @ h        (bf16)
__device__ __align__(16) unsigned short g_p2[NN * DD];          // M2 @ h + Mb   (bf16)
__device__ __align__(16) unsigned short g_x2[NN * XW];          // agg stats bf16
__device__ __align__(16) float          g_sc[NN * 2];           // per-node (s1, s2)
__device__ __align__(16) unsigned short g_BfragU[NL * 26 * 4 * 512]; // W_comb^T fragments
__device__ __align__(16) unsigned short g_BfragM[NL * 4 * 4 * 512];  // M_w^T fragments
__device__ float g_bcomb[NL * DD];
__device__ int   g_cnt8[NCPY * NN];   // per-replica histogram
__device__ int   g_cnt[NN];           // total degree
__device__ int   g_roff[NN + 1];
__device__ int   g_roff8[NCPY * NN];  // roff[n] + prefix of replicas < c
__device__ __align__(16) unsigned short g_csrc[EE];  // src node per CSR row (2B record)
__device__ __align__(16) unsigned short g_epos[EE];  // rank | (copy<<12)
__device__ int   g_bsum[SCAN_BLKS], g_boff[SCAN_BLKS];

__device__ __forceinline__ float bf2f(unsigned short u) {
  return __uint_as_float(((unsigned)u) << 16);
}
__device__ __forceinline__ unsigned short f2bf(float f) {
  unsigned u = __float_as_uint(f);
  return (unsigned short)((u + 0x7FFFu + ((u >> 16) & 1u)) >> 16);
}
__device__ __forceinline__ float lrelu(float x) { return fmaxf(x, x * SLOPE); }

__global__ void __launch_bounds__(256) k_zero() {
  int i = blockIdx.x * 256 + threadIdx.x;
  if (i < NCPY * NN) g_cnt8[i] = 0;
}

// ---- fused: h = round(h*100)/100 -> bf16, plus replicated degree hist + rank ----
__global__ void __launch_bounds__(256) k_prephist(const float* __restrict__ h,
                                                  const int* __restrict__ dst) {
  int i = blockIdx.x * 256 + threadIdx.x;
  if (i < NN * DD) {
    float v = rintf(h[i] * 100.f) / 100.f;
    g_hb[0][i] = f2bf(v);
  }
  if (i < EE) {
    int d = dst[i];
    int c = blockIdx.x & (NCPY - 1);   // ~XCD-local replica
    int p = atomicAdd(&g_cnt8[c * NN + d], 1);
    g_epos[i] = (unsigned short)(p | (c << 12));
  }
}

// ---- scan a: fold replicas -> total degree + per-replica prefix (in g_roff8 tmp) ----
__global__ void __launch_bounds__(256) k_scan_a() {
  __shared__ int sh[256];
  int t = threadIdx.x;
  int idx = blockIdx.x * 256 + t;
  int deg = 0;
  if (idx < NN) {
    int run = 0;
#pragma unroll
    for (int c = 0; c < NCPY; ++c) {
      g_roff8[c * NN + idx] = run;          // replica-prefix (roff added in scan_c)
      run += g_cnt8[c * NN + idx];
    }
    deg = run;
    g_cnt[idx] = deg;
  }
  sh[t] = deg;
  __syncthreads();
  for (int off = 128; off > 0; off >>= 1) {
    if (t < off) sh[t] += sh[t + off];
    __syncthreads();
  }
  if (t == 0) g_bsum[blockIdx.x] = sh[0];
}

__global__ void __launch_bounds__(256) k_scan_b() {
  __shared__ int sh[256];
  int t = threadIdx.x;
  sh[t] = (t < SCAN_BLKS) ? g_bsum[t] : 0;
  __syncthreads();
  for (int off = 1; off < 256; off <<= 1) {
    int v = (t >= off) ? sh[t - off] : 0;
    __syncthreads();
    sh[t] += v;
    __syncthreads();
  }
  if (t < SCAN_BLKS) g_boff[t] = (t == 0) ? 0 : sh[t - 1];
}

__global__ void __launch_bounds__(256) k_scan_c() {
  __shared__ int sh[256];
  int t = threadIdx.x;
  int idx = blockIdx.x * 256 + t;
  int v = (idx < NN) ? g_cnt[idx] : 0;
  sh[t] = v;
  __syncthreads();
  for (int off = 1; off < 256; off <<= 1) {
    int x = (t >= off) ? sh[t - off] : 0;
    __syncthreads();
    sh[t] += x;
    __syncthreads();
  }
  if (idx < NN) {
    int ro = g_boff[blockIdx.x] + sh[t] - v;   // exclusive prefix
    g_roff[idx] = ro;
#pragma unroll
    for (int c = 0; c < NCPY; ++c) g_roff8[c * NN + idx] += ro;
  }
  if (blockIdx.x == 0 && t == 0) g_roff[NN] = EE;
}

// ---- scatter, position-range grouped: group g = blockIdx&7 writes only
//      positions [g*EE/8, (g+1)*EE/8). Coverage independent of XCD mapping;
//      with round-robin mapping each csrc slice stays in one XCD's L2. ----
__global__ void __launch_bounds__(256) k_scatter(const int* __restrict__ src,
                                                 const int* __restrict__ dst) {
  int g = blockIdx.x & (SGRP - 1);
  int bid = blockIdx.x >> 3;
  const int nb = SCAT_BLKS / SGRP;          // 391 blocks per group
  int lo = g * (EE / SGRP), hi = lo + EE / SGRP;
  for (int i = bid * 256 + threadIdx.x; i < EE; i += nb * 256) {
    int d = dst[i];
    int e = (int)g_epos[i];
    int c = e >> 12, rank = e & 0xFFF;
    int pos = g_roff8[c * NN + d] + rank;
    if (pos >= lo && pos < hi)
      g_csrc[pos] = (unsigned short)src[i];
  }
}

// ---- fused weight prep: W_comb fragments + M fragments + combined bias ----
__global__ void __launch_bounds__(256) k_weights(const float* __restrict__ Uw,
                                                 const float* __restrict__ mixw,
                                                 const float* __restrict__ Mw,
                                                 const float* __restrict__ Ub,
                                                 const float* __restrict__ mixb) {
  int idx = blockIdx.x * 256 + threadIdx.x;
  if (idx < NL * DD * UIN) {   // W_comb = mix_w @ U_w -> B-fragment layout
    int l = idx / (DD * UIN);
    int rem = idx - l * (DD * UIN);
    int d = rem / UIN;
    int k = rem - d * UIN;
    const float* xw = mixw + (l * DD + d) * DD;
    const float* uc = Uw + (size_t)l * DD * UIN + k;
    float s = 0.f;
    for (int j = 0; j < DD; ++j) s += xw[j] * uc[(size_t)j * UIN];
    int kt = k >> 5, kr = k & 31, g = kr >> 3, j8 = kr & 7, nb = d >> 4;
    int ln = (g << 4) | (d & 15);
    g_BfragU[(((l * 26 + kt) * 4 + nb) << 9) + ln * 8 + j8] = f2bf(s);
  }
  if (idx < NL * DD * 128) {   // M_w -> B-fragment layout
    int l = idx >> 13;
    int rem = idx & 8191;
    int d = rem >> 7;
    int k = rem & 127;
    float w = Mw[idx];
    int kt = k >> 5, kr = k & 31, g = kr >> 3, j8 = kr & 7, nb = d >> 4;
    int ln = (g << 4) | (d & 15);
    g_BfragM[(((l * 4 + kt) * 4 + nb) << 9) + ln * 8 + j8] = f2bf(w);
  }
  if (idx < NL * DD) {         // b_comb = mix_w @ U_b + mix_b
    int l = idx >> 6, d = idx & 63;
    const float* xw = mixw + (l * DD + d) * DD;
    const float* ub = Ub + l * DD;
    float s = 0.f;
    for (int j = 0; j < DD; ++j) s += xw[j] * ub[j];
    g_bcomb[idx] = s + mixb[idx];
  }
}

// ---- per-node pre-GEMM (every layer): p1 = M1@h, p2 = M2@h + Mb ----
__global__ void __launch_bounds__(256, 2) k_pre(const float* __restrict__ Mb,
                                                int L, int par) {
  int lane = threadIdx.x & 63;
  int nb = threadIdx.x >> 6;
  int chunk = (lane >> 4) << 3;
  const unsigned short* bp = g_BfragM + (size_t)L * 16 * 512;
  short8 B1[2], B2[2];
#pragma unroll
  for (int kt = 0; kt < 2; ++kt) {
    B1[kt] = *(const short8*)(bp + ((kt * 4 + nb) << 9) + lane * 8);        // M1 (K 0..63)
    B2[kt] = *(const short8*)(bp + (((kt + 2) * 4 + nb) << 9) + lane * 8);  // M2 (K 64..127)
  }
  float mb = Mb[L * DD + nb * 16 + (lane & 15)];
  const unsigned short* hb = g_hb[par];

  for (int wt = blockIdx.x; wt < NTILE; wt += gridDim.x) {
    int rowA = wt * 16 + (lane & 15);
    const unsigned short* hp = hb + (size_t)rowA * DD;
    floatx4 a1, a2;
#pragma unroll
    for (int r = 0; r < 4; ++r) { a1[r] = 0.f; a2[r] = 0.f; }
#pragma unroll
    for (int kt = 0; kt < 2; ++kt) {
      short8 a = *(const short8*)(hp + kt * 32 + chunk);
      a1 = __builtin_amdgcn_mfma_f32_16x16x32_bf16(a, B1[kt], a1, 0, 0, 0);
      a2 = __builtin_amdgcn_mfma_f32_16x16x32_bf16(a, B2[kt], a2, 0, 0, 0);
    }
#pragma unroll
    for (int r = 0; r < 4; ++r) {
      int row = wt * 16 + 4 * (lane >> 4) + r;
      int col = nb * 16 + (lane & 15);
      g_p1[row * DD + col] = f2bf(a1[r]);
      g_p2[row * DD + col] = f2bf(a2[r] + mb);
    }
  }
}

// ---- fused message+aggregation: msg = lrelu(p1[src] + p2[n]) on the fly ----
// 2 nodes per wave: lanes 0-31 own node 2k, lanes 32-63 own node 2k+1.
#define AGG_PROC(v)                                              \
  {                                                              \
    float lo = __uint_as_float((v) << 16) + b0;                  \
    float hi = __uint_as_float((v) & 0xffff0000u) + b1;          \
    lo = fmaxf(lo, lo * SLOPE);                                  \
    hi = fmaxf(hi, hi * SLOPE);                                  \
    s0 += lo; q0 += lo * lo; mx0 = fmaxf(mx0, lo); mn0 = fminf(mn0, lo); \
    s1 += hi; q1 += hi * hi; mx1 = fmaxf(mx1, hi); mn1 = fminf(mn1, hi); \
  }

__global__ void __launch_bounds__(256) k_aggf() {
  int lane = threadIdx.x & 63;
  int wid = threadIdx.x >> 6;
  int c2 = lane & 31;              // column-pair index (cols 2c2, 2c2+1)
  int hbase = lane & 32;           // 0 for half 0, 32 for half 1 (shfl source base)
  int n = blockIdx.x * 8 + wid * 2 + (lane >> 5);
  int r0 = g_roff[n], r1 = g_roff[n + 1];
  const unsigned* p1u = (const unsigned*)g_p1;
  const unsigned* p2u = (const unsigned*)g_p2;
  unsigned pv = p2u[(size_t)n * 32 + c2];
  float b0 = __uint_as_float(pv << 16);
  float b1 = __uint_as_float(pv & 0xffff0000u);
  float s0 = 0.f, q0 = 0.f, mx0 = -3.4e38f, mn0 = 3.4e38f;
  float s1 = 0.f, q1 = 0.f, mx1 = -3.4e38f, mn1 = 3.4e38f;
  for (int base = r0; base < r1; base += 32) {
    int m = min(32, r1 - base);
    int sv = (c2 < m) ? (int)g_csrc[base + c2] : 0;  // each half: coalesced 64B
    int j = 0;
    // 4 independent gathers in flight per half-wave
    for (; j + 3 < m; j += 4) {
      int sn0 = __shfl(sv, hbase + j);
      int sn1 = __shfl(sv, hbase + j + 1);
      int sn2 = __shfl(sv, hbase + j + 2);
      int sn3 = __shfl(sv, hbase + j + 3);
      unsigned v0 = p1u[(size_t)sn0 * 32 + c2];
      unsigned v1 = p1u[(size_t)sn1 * 32 + c2];
      unsigned v2 = p1u[(size_t)sn2 * 32 + c2];
      unsigned v3 = p1u[(size_t)sn3 * 32 + c2];
      AGG_PROC(v0); AGG_PROC(v1); AGG_PROC(v2); AGG_PROC(v3);
    }
    for (; j < m; ++j) {
      int sn = __shfl(sv, hbase + j);
      unsigned v = p1u[(size_t)sn * 32 + c2];
      AGG_PROC(v);
    }
  }
  int deg = r1 - r0;
  float degc = fmaxf((float)deg, 1.f);
  float mean0 = s0 / degc, mean1 = s1 / degc;
  float sd0 = sqrtf(fmaxf(q0 / degc - mean0 * mean0, 0.f) + 1e-30f);
  float sd1 = sqrtf(fmaxf(q1 / degc - mean1 * mean1, 0.f) + 1e-30f);
  if (deg == 0) { mx0 = 0.f; mx1 = 0.f; mn0 = 0.f; mn1 = 0.f; sd0 = 0.f; sd1 = 0.f; }
  unsigned* xp = (unsigned*)(g_x2 + (size_t)n * XW);
  xp[c2]      = (unsigned)f2bf(mean0) | ((unsigned)f2bf(mean1) << 16);
  xp[32 + c2] = (unsigned)f2bf(mx0)   | ((unsigned)f2bf(mx1)   << 16);
  xp[64 + c2] = (unsigned)f2bf(mn0)   | ((unsigned)f2bf(mn1)   << 16);
  xp[96 + c2] = (unsigned)f2bf(sd0)   | ((unsigned)f2bf(sd1)   << 16);
  if (c2 == 0) {
    float logd = logf(degc + 1.f);
    g_sc[n * 2] = logd / DELTA_F;
    g_sc[n * 2 + 1] = DELTA_F / logd;
  }
}

// ---- fused U+mix GEMM, N-split across waves (pure streaming: no LDS, no barriers) ----
__global__ void __launch_bounds__(256, 2) k_update(int L, int par, float* __restrict__ out) {
  int lane = threadIdx.x & 63;
  int nb = threadIdx.x >> 6;         // wave id == output col block
  int chunk = (lane >> 4) << 3;
  const unsigned short* bp = g_BfragU + (size_t)L * 26 * 4 * 512;

  // load this wave's B fragments once
  short8 Bf[26];
#pragma unroll
  for (int i = 0; i < 26; ++i)
    Bf[i] = *(const short8*)(bp + ((i * 4 + nb) << 9) + lane * 8);
  float bc = g_bcomb[L * DD + nb * 16 + (lane & 15)];
  const unsigned short* hb = g_hb[par];
  unsigned short* hbn = g_hb[par ^ 1];

  float csum = 0.f;
  for (int wt = blockIdx.x; wt < NTILE; wt += gridDim.x) {
    int rbase = wt * 16;
    int rowA = rbase + (lane & 15);
    const unsigned short* hp = hb + (size_t)rowA * DD;
    const unsigned short* ap = g_x2 + (size_t)rowA * XW;
    floatx4 acc0, acc2, acc3;
#pragma unroll
    for (int r = 0; r < 4; ++r) { acc0[r] = 0.f; acc2[r] = 0.f; acc3[r] = 0.f; }
    // group 0: kt 0,1 = h; kt 2..9 = agg
#pragma unroll
    for (int kk = 0; kk < 10; ++kk) {
      short8 a = (kk < 2) ? *(const short8*)(hp + kk * 32 + chunk)
                          : *(const short8*)(ap + (kk - 2) * 32 + chunk);
      acc0 = __builtin_amdgcn_mfma_f32_16x16x32_bf16(a, Bf[kk], acc0, 0, 0, 0);
    }
    // groups 2,3: kt 10..17 and 18..25 over the SAME agg cols
#pragma unroll
    for (int kk = 0; kk < 8; ++kk) {
      short8 a = *(const short8*)(ap + kk * 32 + chunk);
      acc2 = __builtin_amdgcn_mfma_f32_16x16x32_bf16(a, Bf[10 + kk], acc2, 0, 0, 0);
      acc3 = __builtin_amdgcn_mfma_f32_16x16x32_bf16(a, Bf[18 + kk], acc3, 0, 0, 0);
    }
    // epilogue: scalers, leaky, residual (bf16), relu, store
#pragma unroll
    for (int r = 0; r < 4; ++r) {
      int row = rbase + 4 * (lane >> 4) + r;
      float s1 = g_sc[row * 2], s2 = g_sc[row * 2 + 1];
      int col = nb * 16 + (lane & 15);
      float y = lrelu(acc0[r] + s1 * acc2[r] + s2 * acc3[r] + bc);
      float hn = fmaxf(y + bf2f(hb[row * DD + col]), 0.f);
      hbn[row * DD + col] = f2bf(hn);
      csum += hn;
    }
  }
  if (L == 2) {
    csum += __shfl_xor(csum, 16);
    csum += __shfl_xor(csum, 32);
    if ((lane >> 4) == 0) atomicAdd(out + nb * 16 + lane, csum);
  }
}

extern "C" void kernel_launch(void* const* d_in, const int* in_sizes, int n_in,
                              void* d_out, int out_size, void* d_ws, size_t ws_size,
                              hipStream_t stream) {
  const float* h    = (const float*)d_in[0];
  const int*   src  = (const int*)d_in[1];
  const int*   dst  = (const int*)d_in[2];
  const float* Mw   = (const float*)d_in[3];
  const float* Mb   = (const float*)d_in[4];
  const float* Uw   = (const float*)d_in[5];
  const float* Ub   = (const float*)d_in[6];
  const float* mixw = (const float*)d_in[7];
  const float* mixb = (const float*)d_in[8];
  float* out = (float*)d_out;

  hipMemsetAsync(out, 0, (size_t)out_size * sizeof(float), stream);

  k_zero<<<1563, 256, 0, stream>>>();              // zero 8 histogram replicas
  k_prephist<<<12500, 256, 0, stream>>>(h, dst);   // h prep + replicated hist + ranks
  k_scan_a<<<SCAN_BLKS, 256, 0, stream>>>();
  k_scan_b<<<1, 256, 0, stream>>>();
  k_scan_c<<<SCAN_BLKS, 256, 0, stream>>>();
  k_scatter<<<SCAT_BLKS, 256, 0, stream>>>(src, dst);  // position-range grouped
  k_weights<<<624, 256, 0, stream>>>(Uw, mixw, Mw, Ub, mixb);

  for (int L = 0; L < NL; ++L) {
    int par = L & 1;
    k_pre<<<UPD_BLKS, 256, 0, stream>>>(Mb, L, par);
    k_aggf<<<6250, 256, 0, stream>>>();            // 8 nodes per block (2 per wave)
    k_update<<<UPD_BLKS, 256, 0, stream>>>(L, par, out);
  }
}

// Round 22
// 259.740 us; speedup vs baseline: 1.1735x; 1.1735x over previous
//
#include <hip/hip_runtime.h>

#define NN 50000
#define EE 800000
#define DD 64
#define NL 3
#define UIN 832
#define XW 256   // stored x row: [mean | mx | mn | sd] (h read directly from g_hb)
#define DELTA_F 2.833213344056216f
#define SLOPE 0.01f
#define SCAN_BLKS 196  // 196*256 = 50176 >= NN
#define UPD_BLKS 512
#define NTILE 3125     // NN/16
#define NCPY 8         // histogram replicas (~one per XCD)

typedef __attribute__((ext_vector_type(8))) short short8;
typedef __attribute__((ext_vector_type(4))) float floatx4;

// ---- static device buffers (fully rewritten every call) ----
__device__ __align__(16) unsigned short g_hb[2][NN * DD];       // bf16 h (double buffer)
__device__ __align__(16) unsigned short g_p1[NN * DD];          // M1 @ h        (bf16)
__device__ __align__(16) unsigned short g_p2[NN * DD];          // M2 @ h + Mb   (bf16)
__device__ __align__(16) unsigned short g_x2[NN * XW];          // agg stats bf16
__device__ __align__(16) float          g_sc[NN * 2];           // per-node (s1, s2)
__device__ __align__(16) unsigned short g_BfragU[NL * 26 * 4 * 512]; // W_comb^T fragments
__device__ __align__(16) unsigned short g_BfragM[NL * 4 * 4 * 512];  // M_w^T fragments
__device__ float g_bcomb[NL * DD];
__device__ int   g_cnt8[NCPY * NN];   // per-replica histogram
__device__ int   g_cnt[NN];           // total degree
__device__ int   g_roff[NN + 1];
__device__ int   g_roff8[NCPY * NN];  // roff[n] + prefix of replicas < c
__device__ __align__(16) unsigned short g_csrc[EE];  // src node per CSR row (2B record)
__device__ __align__(16) unsigned short g_epos[EE];  // rank | (copy<<12)
__device__ int   g_bsum[SCAN_BLKS], g_boff[SCAN_BLKS];

__device__ __forceinline__ float bf2f(unsigned short u) {
  return __uint_as_float(((unsigned)u) << 16);
}
__device__ __forceinline__ unsigned short f2bf(float f) {
  unsigned u = __float_as_uint(f);
  return (unsigned short)((u + 0x7FFFu + ((u >> 16) & 1u)) >> 16);
}
__device__ __forceinline__ float lrelu(float x) { return fmaxf(x, x * SLOPE); }

__global__ void __launch_bounds__(256) k_zero() {
  int i = blockIdx.x * 256 + threadIdx.x;
  if (i < NCPY * NN) g_cnt8[i] = 0;
}

// ---- fused: h = round(h*100)/100 -> bf16, plus replicated degree hist + rank ----
__global__ void __launch_bounds__(256) k_prephist(const float* __restrict__ h,
                                                  const int* __restrict__ dst) {
  int i = blockIdx.x * 256 + threadIdx.x;
  if (i < NN * DD) {
    float v = rintf(h[i] * 100.f) / 100.f;
    g_hb[0][i] = f2bf(v);
  }
  if (i < EE) {
    int d = dst[i];
    int c = blockIdx.x & (NCPY - 1);   // ~XCD-local replica
    int p = atomicAdd(&g_cnt8[c * NN + d], 1);
    g_epos[i] = (unsigned short)(p | (c << 12));
  }
}

// ---- scan a: fold replicas -> total degree + per-replica prefix (in g_roff8 tmp) ----
__global__ void __launch_bounds__(256) k_scan_a() {
  __shared__ int sh[256];
  int t = threadIdx.x;
  int idx = blockIdx.x * 256 + t;
  int deg = 0;
  if (idx < NN) {
    int run = 0;
#pragma unroll
    for (int c = 0; c < NCPY; ++c) {
      g_roff8[c * NN + idx] = run;          // replica-prefix (roff added in scan_c)
      run += g_cnt8[c * NN + idx];
    }
    deg = run;
    g_cnt[idx] = deg;
  }
  sh[t] = deg;
  __syncthreads();
  for (int off = 128; off > 0; off >>= 1) {
    if (t < off) sh[t] += sh[t + off];
    __syncthreads();
  }
  if (t == 0) g_bsum[blockIdx.x] = sh[0];
}

__global__ void __launch_bounds__(256) k_scan_b() {
  __shared__ int sh[256];
  int t = threadIdx.x;
  sh[t] = (t < SCAN_BLKS) ? g_bsum[t] : 0;
  __syncthreads();
  for (int off = 1; off < 256; off <<= 1) {
    int v = (t >= off) ? sh[t - off] : 0;
    __syncthreads();
    sh[t] += v;
    __syncthreads();
  }
  if (t < SCAN_BLKS) g_boff[t] = (t == 0) ? 0 : sh[t - 1];
}

__global__ void __launch_bounds__(256) k_scan_c() {
  __shared__ int sh[256];
  int t = threadIdx.x;
  int idx = blockIdx.x * 256 + t;
  int v = (idx < NN) ? g_cnt[idx] : 0;
  sh[t] = v;
  __syncthreads();
  for (int off = 1; off < 256; off <<= 1) {
    int x = (t >= off) ? sh[t - off] : 0;
    __syncthreads();
    sh[t] += x;
    __syncthreads();
  }
  if (idx < NN) {
    int ro = g_boff[blockIdx.x] + sh[t] - v;   // exclusive prefix
    g_roff[idx] = ro;
#pragma unroll
    for (int c = 0; c < NCPY; ++c) g_roff8[c * NN + idx] += ro;
  }
  if (blockIdx.x == 0 && t == 0) g_roff[NN] = EE;
}

// ---- scatter: pos = roff8[copy][d] + rank — no atomic, one 4B gather + 2B store ----
__global__ void __launch_bounds__(256) k_scatter(const int* __restrict__ src,
                                                 const int* __restrict__ dst) {
  int i = blockIdx.x * 256 + threadIdx.x;
  if (i < EE) {
    int d = dst[i];
    int e = (int)g_epos[i];
    int c = e >> 12, rank = e & 0xFFF;
    g_csrc[g_roff8[c * NN + d] + rank] = (unsigned short)src[i];
  }
}

// ---- fused weight prep: W_comb fragments + M fragments + combined bias ----
__global__ void __launch_bounds__(256) k_weights(const float* __restrict__ Uw,
                                                 const float* __restrict__ mixw,
                                                 const float* __restrict__ Mw,
                                                 const float* __restrict__ Ub,
                                                 const float* __restrict__ mixb) {
  int idx = blockIdx.x * 256 + threadIdx.x;
  if (idx < NL * DD * UIN) {   // W_comb = mix_w @ U_w -> B-fragment layout
    int l = idx / (DD * UIN);
    int rem = idx - l * (DD * UIN);
    int d = rem / UIN;
    int k = rem - d * UIN;
    const float* xw = mixw + (l * DD + d) * DD;
    const float* uc = Uw + (size_t)l * DD * UIN + k;
    float s = 0.f;
    for (int j = 0; j < DD; ++j) s += xw[j] * uc[(size_t)j * UIN];
    int kt = k >> 5, kr = k & 31, g = kr >> 3, j8 = kr & 7, nb = d >> 4;
    int ln = (g << 4) | (d & 15);
    g_BfragU[(((l * 26 + kt) * 4 + nb) << 9) + ln * 8 + j8] = f2bf(s);
  }
  if (idx < NL * DD * 128) {   // M_w -> B-fragment layout
    int l = idx >> 13;
    int rem = idx & 8191;
    int d = rem >> 7;
    int k = rem & 127;
    float w = Mw[idx];
    int kt = k >> 5, kr = k & 31, g = kr >> 3, j8 = kr & 7, nb = d >> 4;
    int ln = (g << 4) | (d & 15);
    g_BfragM[(((l * 4 + kt) * 4 + nb) << 9) + ln * 8 + j8] = f2bf(w);
  }
  if (idx < NL * DD) {         // b_comb = mix_w @ U_b + mix_b
    int l = idx >> 6, d = idx & 63;
    const float* xw = mixw + (l * DD + d) * DD;
    const float* ub = Ub + l * DD;
    float s = 0.f;
    for (int j = 0; j < DD; ++j) s += xw[j] * ub[j];
    g_bcomb[idx] = s + mixb[idx];
  }
}

// ---- per-node pre-GEMM (every layer): p1 = M1@h, p2 = M2@h + Mb ----
__global__ void __launch_bounds__(256, 2) k_pre(const float* __restrict__ Mb,
                                                int L, int par) {
  int lane = threadIdx.x & 63;
  int nb = threadIdx.x >> 6;
  int chunk = (lane >> 4) << 3;
  const unsigned short* bp = g_BfragM + (size_t)L * 16 * 512;
  short8 B1[2], B2[2];
#pragma unroll
  for (int kt = 0; kt < 2; ++kt) {
    B1[kt] = *(const short8*)(bp + ((kt * 4 + nb) << 9) + lane * 8);        // M1 (K 0..63)
    B2[kt] = *(const short8*)(bp + (((kt + 2) * 4 + nb) << 9) + lane * 8);  // M2 (K 64..127)
  }
  float mb = Mb[L * DD + nb * 16 + (lane & 15)];
  const unsigned short* hb = g_hb[par];

  for (int wt = blockIdx.x; wt < NTILE; wt += gridDim.x) {
    int rowA = wt * 16 + (lane & 15);
    const unsigned short* hp = hb + (size_t)rowA * DD;
    floatx4 a1, a2;
#pragma unroll
    for (int r = 0; r < 4; ++r) { a1[r] = 0.f; a2[r] = 0.f; }
#pragma unroll
    for (int kt = 0; kt < 2; ++kt) {
      short8 a = *(const short8*)(hp + kt * 32 + chunk);
      a1 = __builtin_amdgcn_mfma_f32_16x16x32_bf16(a, B1[kt], a1, 0, 0, 0);
      a2 = __builtin_amdgcn_mfma_f32_16x16x32_bf16(a, B2[kt], a2, 0, 0, 0);
    }
#pragma unroll
    for (int r = 0; r < 4; ++r) {
      int row = wt * 16 + 4 * (lane >> 4) + r;
      int col = nb * 16 + (lane & 15);
      g_p1[row * DD + col] = f2bf(a1[r]);
      g_p2[row * DD + col] = f2bf(a2[r] + mb);
    }
  }
}

// ---- fused message+aggregation: msg = lrelu(p1[src] + p2[n]) on the fly ----
// 2 nodes per wave: lanes 0-31 own node 2k, lanes 32-63 own node 2k+1.
#define AGG_PROC(v)                                              \
  {                                                              \
    float lo = __uint_as_float((v) << 16) + b0;                  \
    float hi = __uint_as_float((v) & 0xffff0000u) + b1;          \
    lo = fmaxf(lo, lo * SLOPE);                                  \
    hi = fmaxf(hi, hi * SLOPE);                                  \
    s0 += lo; q0 += lo * lo; mx0 = fmaxf(mx0, lo); mn0 = fminf(mn0, lo); \
    s1 += hi; q1 += hi * hi; mx1 = fmaxf(mx1, hi); mn1 = fminf(mn1, hi); \
  }

__global__ void __launch_bounds__(256) k_aggf() {
  int lane = threadIdx.x & 63;
  int wid = threadIdx.x >> 6;
  int c2 = lane & 31;              // column-pair index (cols 2c2, 2c2+1)
  int hbase = lane & 32;           // 0 for half 0, 32 for half 1 (shfl source base)
  int n = blockIdx.x * 8 + wid * 2 + (lane >> 5);
  int r0 = g_roff[n], r1 = g_roff[n + 1];
  const unsigned* p1u = (const unsigned*)g_p1;
  const unsigned* p2u = (const unsigned*)g_p2;
  unsigned pv = p2u[(size_t)n * 32 + c2];
  float b0 = __uint_as_float(pv << 16);
  float b1 = __uint_as_float(pv & 0xffff0000u);
  float s0 = 0.f, q0 = 0.f, mx0 = -3.4e38f, mn0 = 3.4e38f;
  float s1 = 0.f, q1 = 0.f, mx1 = -3.4e38f, mn1 = 3.4e38f;
  for (int base = r0; base < r1; base += 32) {
    int m = min(32, r1 - base);
    int sv = (c2 < m) ? (int)g_csrc[base + c2] : 0;  // each half: coalesced 64B
    int j = 0;
    // 4 independent gathers in flight per half-wave
    for (; j + 3 < m; j += 4) {
      int sn0 = __shfl(sv, hbase + j);
      int sn1 = __shfl(sv, hbase + j + 1);
      int sn2 = __shfl(sv, hbase + j + 2);
      int sn3 = __shfl(sv, hbase + j + 3);
      unsigned v0 = p1u[(size_t)sn0 * 32 + c2];
      unsigned v1 = p1u[(size_t)sn1 * 32 + c2];
      unsigned v2 = p1u[(size_t)sn2 * 32 + c2];
      unsigned v3 = p1u[(size_t)sn3 * 32 + c2];
      AGG_PROC(v0); AGG_PROC(v1); AGG_PROC(v2); AGG_PROC(v3);
    }
    for (; j < m; ++j) {
      int sn = __shfl(sv, hbase + j);
      unsigned v = p1u[(size_t)sn * 32 + c2];
      AGG_PROC(v);
    }
  }
  int deg = r1 - r0;
  float degc = fmaxf((float)deg, 1.f);
  float mean0 = s0 / degc, mean1 = s1 / degc;
  float sd0 = sqrtf(fmaxf(q0 / degc - mean0 * mean0, 0.f) + 1e-30f);
  float sd1 = sqrtf(fmaxf(q1 / degc - mean1 * mean1, 0.f) + 1e-30f);
  if (deg == 0) { mx0 = 0.f; mx1 = 0.f; mn0 = 0.f; mn1 = 0.f; sd0 = 0.f; sd1 = 0.f; }
  unsigned* xp = (unsigned*)(g_x2 + (size_t)n * XW);
  xp[c2]      = (unsigned)f2bf(mean0) | ((unsigned)f2bf(mean1) << 16);
  xp[32 + c2] = (unsigned)f2bf(mx0)   | ((unsigned)f2bf(mx1)   << 16);
  xp[64 + c2] = (unsigned)f2bf(mn0)   | ((unsigned)f2bf(mn1)   << 16);
  xp[96 + c2] = (unsigned)f2bf(sd0)   | ((unsigned)f2bf(sd1)   << 16);
  if (c2 == 0) {
    float logd = logf(degc + 1.f);
    g_sc[n * 2] = logd / DELTA_F;
    g_sc[n * 2 + 1] = DELTA_F / logd;
  }
}

// ---- fused U+mix GEMM, N-split across waves (pure streaming: no LDS, no barriers) ----
__global__ void __launch_bounds__(256, 2) k_update(int L, int par, float* __restrict__ out) {
  int lane = threadIdx.x & 63;
  int nb = threadIdx.x >> 6;         // wave id == output col block
  int chunk = (lane >> 4) << 3;
  const unsigned short* bp = g_BfragU + (size_t)L * 26 * 4 * 512;

  // load this wave's B fragments once
  short8 Bf[26];
#pragma unroll
  for (int i = 0; i < 26; ++i)
    Bf[i] = *(const short8*)(bp + ((i * 4 + nb) << 9) + lane * 8);
  float bc = g_bcomb[L * DD + nb * 16 + (lane & 15)];
  const unsigned short* hb = g_hb[par];
  unsigned short* hbn = g_hb[par ^ 1];

  float csum = 0.f;
  for (int wt = blockIdx.x; wt < NTILE; wt += gridDim.x) {
    int rbase = wt * 16;
    int rowA = rbase + (lane & 15);
    const unsigned short* hp = hb + (size_t)rowA * DD;
    const unsigned short* ap = g_x2 + (size_t)rowA * XW;
    floatx4 acc0, acc2, acc3;
#pragma unroll
    for (int r = 0; r < 4; ++r) { acc0[r] = 0.f; acc2[r] = 0.f; acc3[r] = 0.f; }
    // group 0: kt 0,1 = h; kt 2..9 = agg
#pragma unroll
    for (int kk = 0; kk < 10; ++kk) {
      short8 a = (kk < 2) ? *(const short8*)(hp + kk * 32 + chunk)
                          : *(const short8*)(ap + (kk - 2) * 32 + chunk);
      acc0 = __builtin_amdgcn_mfma_f32_16x16x32_bf16(a, Bf[kk], acc0, 0, 0, 0);
    }
    // groups 2,3: kt 10..17 and 18..25 over the SAME agg cols
#pragma unroll
    for (int kk = 0; kk < 8; ++kk) {
      short8 a = *(const short8*)(ap + kk * 32 + chunk);
      acc2 = __builtin_amdgcn_mfma_f32_16x16x32_bf16(a, Bf[10 + kk], acc2, 0, 0, 0);
      acc3 = __builtin_amdgcn_mfma_f32_16x16x32_bf16(a, Bf[18 + kk], acc3, 0, 0, 0);
    }
    // epilogue: scalers, leaky, residual (bf16), relu, store
#pragma unroll
    for (int r = 0; r < 4; ++r) {
      int row = rbase + 4 * (lane >> 4) + r;
      float s1 = g_sc[row * 2], s2 = g_sc[row * 2 + 1];
      int col = nb * 16 + (lane & 15);
      float y = lrelu(acc0[r] + s1 * acc2[r] + s2 * acc3[r] + bc);
      float hn = fmaxf(y + bf2f(hb[row * DD + col]), 0.f);
      hbn[row * DD + col] = f2bf(hn);
      csum += hn;
    }
  }
  if (L == 2) {
    csum += __shfl_xor(csum, 16);
    csum += __shfl_xor(csum, 32);
    if ((lane >> 4) == 0) atomicAdd(out + nb * 16 + lane, csum);
  }
}

extern "C" void kernel_launch(void* const* d_in, const int* in_sizes, int n_in,
                              void* d_out, int out_size, void* d_ws, size_t ws_size,
                              hipStream_t stream) {
  const float* h    = (const float*)d_in[0];
  const int*   src  = (const int*)d_in[1];
  const int*   dst  = (const int*)d_in[2];
  const float* Mw   = (const float*)d_in[3];
  const float* Mb   = (const float*)d_in[4];
  const float* Uw   = (const float*)d_in[5];
  const float* Ub   = (const float*)d_in[6];
  const float* mixw = (const float*)d_in[7];
  const float* mixb = (const float*)d_in[8];
  float* out = (float*)d_out;

  hipMemsetAsync(out, 0, (size_t)out_size * sizeof(float), stream);

  k_zero<<<1563, 256, 0, stream>>>();              // zero 8 histogram replicas
  k_prephist<<<12500, 256, 0, stream>>>(h, dst);   // h prep + replicated hist + ranks
  k_scan_a<<<SCAN_BLKS, 256, 0, stream>>>();
  k_scan_b<<<1, 256, 0, stream>>>();
  k_scan_c<<<SCAN_BLKS, 256, 0, stream>>>();
  k_scatter<<<3125, 256, 0, stream>>>(src, dst);   // atomic-free CSR fill
  k_weights<<<624, 256, 0, stream>>>(Uw, mixw, Mw, Ub, mixb);

  for (int L = 0; L < NL; ++L) {
    int par = L & 1;
    k_pre<<<UPD_BLKS, 256, 0, stream>>>(Mb, L, par);
    k_aggf<<<6250, 256, 0, stream>>>();            // 8 nodes per block (2 per wave)
    k_update<<<UPD_BLKS, 256, 0, stream>>>(L, par, out);
  }
}

// Round 23
// 254.974 us; speedup vs baseline: 1.1954x; 1.0187x over previous
//
#include <hip/hip_runtime.h>

#define NN 50000
#define EE 800000
#define DD 64
#define NL 3
#define UIN 832
#define XW 256   // stored x row: [mean | mx | mn | sd] (h read directly from g_hb)
#define DELTA_F 2.833213344056216f
#define SLOPE 0.01f
#define SCAN_BLKS 196  // 196*256 = 50176 >= NN
#define UPD_BLKS 512
#define NTILE 3125     // NN/16
#define NCPY 8         // histogram replicas (~one per XCD)

typedef __attribute__((ext_vector_type(8))) short short8;
typedef __attribute__((ext_vector_type(4))) float floatx4;

// ---- static device buffers (fully rewritten every call) ----
__device__ __align__(16) unsigned short g_hb[2][NN * DD];       // bf16 h (double buffer)
__device__ __align__(16) unsigned short g_p1[NN * DD];          // M1 @ h        (bf16)
__device__ __align__(16) unsigned short g_p2[NN * DD];          // M2 @ h + Mb   (bf16)
__device__ __align__(16) unsigned short g_x2[NN * XW];          // agg stats bf16
__device__ __align__(16) float          g_sc[NN * 2];           // per-node (s1, s2)
__device__ __align__(16) unsigned short g_BfragU[NL * 26 * 4 * 512]; // W_comb^T fragments
__device__ __align__(16) unsigned short g_BfragM[NL * 4 * 4 * 512];  // M_w^T fragments
__device__ float g_bcomb[NL * DD];
__device__ int   g_cnt8[NCPY * NN];   // per-replica histogram
__device__ int   g_cnt[NN];           // total degree
__device__ int   g_roff[NN + 1];
__device__ int   g_roff8[NCPY * NN];  // roff[n] + prefix of replicas < c
__device__ __align__(16) unsigned short g_csrc[EE];  // src node per CSR row (2B record)
__device__ __align__(16) unsigned short g_epos[EE];  // rank | (copy<<12)
__device__ int   g_bsum[SCAN_BLKS], g_boff[SCAN_BLKS];

__device__ __forceinline__ float bf2f(unsigned short u) {
  return __uint_as_float(((unsigned)u) << 16);
}
__device__ __forceinline__ unsigned short f2bf(float f) {
  unsigned u = __float_as_uint(f);
  return (unsigned short)((u + 0x7FFFu + ((u >> 16) & 1u)) >> 16);
}
__device__ __forceinline__ float lrelu(float x) { return fmaxf(x, x * SLOPE); }

__global__ void __launch_bounds__(256) k_zero() {
  int i = blockIdx.x * 256 + threadIdx.x;
  if (i < NCPY * NN) g_cnt8[i] = 0;
}

// ---- fused: h = round(h*100)/100 -> bf16, plus replicated degree hist + rank ----
__global__ void __launch_bounds__(256) k_prephist(const float* __restrict__ h,
                                                  const int* __restrict__ dst) {
  int i = blockIdx.x * 256 + threadIdx.x;
  if (i < NN * DD) {
    float v = rintf(h[i] * 100.f) / 100.f;
    g_hb[0][i] = f2bf(v);
  }
  if (i < EE) {
    int d = dst[i];
    int c = blockIdx.x & (NCPY - 1);   // ~XCD-local replica
    int p = atomicAdd(&g_cnt8[c * NN + d], 1);
    g_epos[i] = (unsigned short)(p | (c << 12));
  }
}

// ---- scan a: fold replicas -> total degree + per-replica prefix (in g_roff8 tmp) ----
__global__ void __launch_bounds__(256) k_scan_a() {
  __shared__ int sh[256];
  int t = threadIdx.x;
  int idx = blockIdx.x * 256 + t;
  int deg = 0;
  if (idx < NN) {
    int run = 0;
#pragma unroll
    for (int c = 0; c < NCPY; ++c) {
      g_roff8[c * NN + idx] = run;          // replica-prefix (roff added in scan_c)
      run += g_cnt8[c * NN + idx];
    }
    deg = run;
    g_cnt[idx] = deg;
  }
  sh[t] = deg;
  __syncthreads();
  for (int off = 128; off > 0; off >>= 1) {
    if (t < off) sh[t] += sh[t + off];
    __syncthreads();
  }
  if (t == 0) g_bsum[blockIdx.x] = sh[0];
}

__global__ void __launch_bounds__(256) k_scan_b() {
  __shared__ int sh[256];
  int t = threadIdx.x;
  sh[t] = (t < SCAN_BLKS) ? g_bsum[t] : 0;
  __syncthreads();
  for (int off = 1; off < 256; off <<= 1) {
    int v = (t >= off) ? sh[t - off] : 0;
    __syncthreads();
    sh[t] += v;
    __syncthreads();
  }
  if (t < SCAN_BLKS) g_boff[t] = (t == 0) ? 0 : sh[t - 1];
}

__global__ void __launch_bounds__(256) k_scan_c() {
  __shared__ int sh[256];
  int t = threadIdx.x;
  int idx = blockIdx.x * 256 + t;
  int v = (idx < NN) ? g_cnt[idx] : 0;
  sh[t] = v;
  __syncthreads();
  for (int off = 1; off < 256; off <<= 1) {
    int x = (t >= off) ? sh[t - off] : 0;
    __syncthreads();
    sh[t] += x;
    __syncthreads();
  }
  if (idx < NN) {
    int ro = g_boff[blockIdx.x] + sh[t] - v;   // exclusive prefix
    g_roff[idx] = ro;
#pragma unroll
    for (int c = 0; c < NCPY; ++c) g_roff8[c * NN + idx] += ro;
  }
  if (blockIdx.x == 0 && t == 0) g_roff[NN] = EE;
}

// ---- scatter: pos = roff8[copy][d] + rank — no atomic, one 4B gather + 2B store ----
__global__ void __launch_bounds__(256) k_scatter(const int* __restrict__ src,
                                                 const int* __restrict__ dst) {
  int i = blockIdx.x * 256 + threadIdx.x;
  if (i < EE) {
    int d = dst[i];
    int e = (int)g_epos[i];
    int c = e >> 12, rank = e & 0xFFF;
    g_csrc[g_roff8[c * NN + d] + rank] = (unsigned short)src[i];
  }
}

// ---- fused weight prep: W_comb fragments + M fragments + combined bias ----
__global__ void __launch_bounds__(256) k_weights(const float* __restrict__ Uw,
                                                 const float* __restrict__ mixw,
                                                 const float* __restrict__ Mw,
                                                 const float* __restrict__ Ub,
                                                 const float* __restrict__ mixb) {
  int idx = blockIdx.x * 256 + threadIdx.x;
  if (idx < NL * DD * UIN) {   // W_comb = mix_w @ U_w -> B-fragment layout
    int l = idx / (DD * UIN);
    int rem = idx - l * (DD * UIN);
    int d = rem / UIN;
    int k = rem - d * UIN;
    const float* xw = mixw + (l * DD + d) * DD;
    const float* uc = Uw + (size_t)l * DD * UIN + k;
    float s = 0.f;
    for (int j = 0; j < DD; ++j) s += xw[j] * uc[(size_t)j * UIN];
    int kt = k >> 5, kr = k & 31, g = kr >> 3, j8 = kr & 7, nb = d >> 4;
    int ln = (g << 4) | (d & 15);
    g_BfragU[(((l * 26 + kt) * 4 + nb) << 9) + ln * 8 + j8] = f2bf(s);
  }
  if (idx < NL * DD * 128) {   // M_w -> B-fragment layout
    int l = idx >> 13;
    int rem = idx & 8191;
    int d = rem >> 7;
    int k = rem & 127;
    float w = Mw[idx];
    int kt = k >> 5, kr = k & 31, g = kr >> 3, j8 = kr & 7, nb = d >> 4;
    int ln = (g << 4) | (d & 15);
    g_BfragM[(((l * 4 + kt) * 4 + nb) << 9) + ln * 8 + j8] = f2bf(w);
  }
  if (idx < NL * DD) {         // b_comb = mix_w @ U_b + mix_b
    int l = idx >> 6, d = idx & 63;
    const float* xw = mixw + (l * DD + d) * DD;
    const float* ub = Ub + l * DD;
    float s = 0.f;
    for (int j = 0; j < DD; ++j) s += xw[j] * ub[j];
    g_bcomb[idx] = s + mixb[idx];
  }
}

// ---- per-node pre-GEMM (every layer): p1 = M1@h, p2 = M2@h + Mb ----
__global__ void __launch_bounds__(256, 2) k_pre(const float* __restrict__ Mb,
                                                int L, int par) {
  int lane = threadIdx.x & 63;
  int nb = threadIdx.x >> 6;
  int chunk = (lane >> 4) << 3;
  const unsigned short* bp = g_BfragM + (size_t)L * 16 * 512;
  short8 B1[2], B2[2];
#pragma unroll
  for (int kt = 0; kt < 2; ++kt) {
    B1[kt] = *(const short8*)(bp + ((kt * 4 + nb) << 9) + lane * 8);        // M1 (K 0..63)
    B2[kt] = *(const short8*)(bp + (((kt + 2) * 4 + nb) << 9) + lane * 8);  // M2 (K 64..127)
  }
  float mb = Mb[L * DD + nb * 16 + (lane & 15)];
  const unsigned short* hb = g_hb[par];

  for (int wt = blockIdx.x; wt < NTILE; wt += gridDim.x) {
    int rowA = wt * 16 + (lane & 15);
    const unsigned short* hp = hb + (size_t)rowA * DD;
    floatx4 a1, a2;
#pragma unroll
    for (int r = 0; r < 4; ++r) { a1[r] = 0.f; a2[r] = 0.f; }
#pragma unroll
    for (int kt = 0; kt < 2; ++kt) {
      short8 a = *(const short8*)(hp + kt * 32 + chunk);
      a1 = __builtin_amdgcn_mfma_f32_16x16x32_bf16(a, B1[kt], a1, 0, 0, 0);
      a2 = __builtin_amdgcn_mfma_f32_16x16x32_bf16(a, B2[kt], a2, 0, 0, 0);
    }
#pragma unroll
    for (int r = 0; r < 4; ++r) {
      int row = wt * 16 + 4 * (lane >> 4) + r;
      int col = nb * 16 + (lane & 15);
      g_p1[row * DD + col] = f2bf(a1[r]);
      g_p2[row * DD + col] = f2bf(a2[r] + mb);
    }
  }
}

// ---- fused message+aggregation: msg = lrelu(p1[src] + p2[n]) on the fly ----
// 2 nodes per wave; 8-deep gather pipeline per half (16 in flight per wave).
#define AGG_PROC(v)                                              \
  {                                                              \
    float lo = __uint_as_float((v) << 16) + b0;                  \
    float hi = __uint_as_float((v) & 0xffff0000u) + b1;          \
    lo = fmaxf(lo, lo * SLOPE);                                  \
    hi = fmaxf(hi, hi * SLOPE);                                  \
    s0 += lo; q0 += lo * lo; mx0 = fmaxf(mx0, lo); mn0 = fminf(mn0, lo); \
    s1 += hi; q1 += hi * hi; mx1 = fmaxf(mx1, hi); mn1 = fminf(mn1, hi); \
  }

__global__ void __launch_bounds__(256) k_aggf() {
  int lane = threadIdx.x & 63;
  int wid = threadIdx.x >> 6;
  int c2 = lane & 31;              // column-pair index (cols 2c2, 2c2+1)
  int hbase = lane & 32;           // 0 for half 0, 32 for half 1 (shfl source base)
  int n = blockIdx.x * 8 + wid * 2 + (lane >> 5);
  int r0 = g_roff[n], r1 = g_roff[n + 1];
  const unsigned* p1u = (const unsigned*)g_p1;
  const unsigned* p2u = (const unsigned*)g_p2;
  unsigned pv = p2u[(size_t)n * 32 + c2];
  float b0 = __uint_as_float(pv << 16);
  float b1 = __uint_as_float(pv & 0xffff0000u);
  float s0 = 0.f, q0 = 0.f, mx0 = -3.4e38f, mn0 = 3.4e38f;
  float s1 = 0.f, q1 = 0.f, mx1 = -3.4e38f, mn1 = 3.4e38f;
  for (int base = r0; base < r1; base += 32) {
    int m = min(32, r1 - base);
    int sv = (c2 < m) ? (int)g_csrc[base + c2] : 0;  // each half: coalesced 64B
    int j = 0;
    // 8 independent gathers in flight per half-wave
    for (; j + 7 < m; j += 8) {
      int sn0 = __shfl(sv, hbase + j);
      int sn1 = __shfl(sv, hbase + j + 1);
      int sn2 = __shfl(sv, hbase + j + 2);
      int sn3 = __shfl(sv, hbase + j + 3);
      int sn4 = __shfl(sv, hbase + j + 4);
      int sn5 = __shfl(sv, hbase + j + 5);
      int sn6 = __shfl(sv, hbase + j + 6);
      int sn7 = __shfl(sv, hbase + j + 7);
      unsigned v0 = p1u[(size_t)sn0 * 32 + c2];
      unsigned v1 = p1u[(size_t)sn1 * 32 + c2];
      unsigned v2 = p1u[(size_t)sn2 * 32 + c2];
      unsigned v3 = p1u[(size_t)sn3 * 32 + c2];
      unsigned v4 = p1u[(size_t)sn4 * 32 + c2];
      unsigned v5 = p1u[(size_t)sn5 * 32 + c2];
      unsigned v6 = p1u[(size_t)sn6 * 32 + c2];
      unsigned v7 = p1u[(size_t)sn7 * 32 + c2];
      AGG_PROC(v0); AGG_PROC(v1); AGG_PROC(v2); AGG_PROC(v3);
      AGG_PROC(v4); AGG_PROC(v5); AGG_PROC(v6); AGG_PROC(v7);
    }
    for (; j + 3 < m; j += 4) {
      int sn0 = __shfl(sv, hbase + j);
      int sn1 = __shfl(sv, hbase + j + 1);
      int sn2 = __shfl(sv, hbase + j + 2);
      int sn3 = __shfl(sv, hbase + j + 3);
      unsigned v0 = p1u[(size_t)sn0 * 32 + c2];
      unsigned v1 = p1u[(size_t)sn1 * 32 + c2];
      unsigned v2 = p1u[(size_t)sn2 * 32 + c2];
      unsigned v3 = p1u[(size_t)sn3 * 32 + c2];
      AGG_PROC(v0); AGG_PROC(v1); AGG_PROC(v2); AGG_PROC(v3);
    }
    for (; j < m; ++j) {
      int sn = __shfl(sv, hbase + j);
      unsigned v = p1u[(size_t)sn * 32 + c2];
      AGG_PROC(v);
    }
  }
  int deg = r1 - r0;
  float degc = fmaxf((float)deg, 1.f);
  float mean0 = s0 / degc, mean1 = s1 / degc;
  float sd0 = sqrtf(fmaxf(q0 / degc - mean0 * mean0, 0.f) + 1e-30f);
  float sd1 = sqrtf(fmaxf(q1 / degc - mean1 * mean1, 0.f) + 1e-30f);
  if (deg == 0) { mx0 = 0.f; mx1 = 0.f; mn0 = 0.f; mn1 = 0.f; sd0 = 0.f; sd1 = 0.f; }
  unsigned* xp = (unsigned*)(g_x2 + (size_t)n * XW);
  xp[c2]      = (unsigned)f2bf(mean0) | ((unsigned)f2bf(mean1) << 16);
  xp[32 + c2] = (unsigned)f2bf(mx0)   | ((unsigned)f2bf(mx1)   << 16);
  xp[64 + c2] = (unsigned)f2bf(mn0)   | ((unsigned)f2bf(mn1)   << 16);
  xp[96 + c2] = (unsigned)f2bf(sd0)   | ((unsigned)f2bf(sd1)   << 16);
  if (c2 == 0) {
    float logd = logf(degc + 1.f);
    g_sc[n * 2] = logd / DELTA_F;
    g_sc[n * 2 + 1] = DELTA_F / logd;
  }
}

// ---- fused U+mix GEMM, N-split across waves (pure streaming: no LDS, no barriers) ----
__global__ void __launch_bounds__(256, 2) k_update(int L, int par, float* __restrict__ out) {
  int lane = threadIdx.x & 63;
  int nb = threadIdx.x >> 6;         // wave id == output col block
  int chunk = (lane >> 4) << 3;
  const unsigned short* bp = g_BfragU + (size_t)L * 26 * 4 * 512;

  // load this wave's B fragments once
  short8 Bf[26];
#pragma unroll
  for (int i = 0; i < 26; ++i)
    Bf[i] = *(const short8*)(bp + ((i * 4 + nb) << 9) + lane * 8);
  float bc = g_bcomb[L * DD + nb * 16 + (lane & 15)];
  const unsigned short* hb = g_hb[par];
  unsigned short* hbn = g_hb[par ^ 1];

  float csum = 0.f;
  for (int wt = blockIdx.x; wt < NTILE; wt += gridDim.x) {
    int rbase = wt * 16;
    int rowA = rbase + (lane & 15);
    const unsigned short* hp = hb + (size_t)rowA * DD;
    const unsigned short* ap = g_x2 + (size_t)rowA * XW;
    floatx4 acc0, acc2, acc3;
#pragma unroll
    for (int r = 0; r < 4; ++r) { acc0[r] = 0.f; acc2[r] = 0.f; acc3[r] = 0.f; }
    // group 0: kt 0,1 = h; kt 2..9 = agg
#pragma unroll
    for (int kk = 0; kk < 10; ++kk) {
      short8 a = (kk < 2) ? *(const short8*)(hp + kk * 32 + chunk)
                          : *(const short8*)(ap + (kk - 2) * 32 + chunk);
      acc0 = __builtin_amdgcn_mfma_f32_16x16x32_bf16(a, Bf[kk], acc0, 0, 0, 0);
    }
    // groups 2,3: kt 10..17 and 18..25 over the SAME agg cols
#pragma unroll
    for (int kk = 0; kk < 8; ++kk) {
      short8 a = *(const short8*)(ap + kk * 32 + chunk);
      acc2 = __builtin_amdgcn_mfma_f32_16x16x32_bf16(a, Bf[10 + kk], acc2, 0, 0, 0);
      acc3 = __builtin_amdgcn_mfma_f32_16x16x32_bf16(a, Bf[18 + kk], acc3, 0, 0, 0);
    }
    // epilogue: scalers, leaky, residual (bf16), relu, store
#pragma unroll
    for (int r = 0; r < 4; ++r) {
      int row = rbase + 4 * (lane >> 4) + r;
      float s1 = g_sc[row * 2], s2 = g_sc[row * 2 + 1];
      int col = nb * 16 + (lane & 15);
      float y = lrelu(acc0[r] + s1 * acc2[r] + s2 * acc3[r] + bc);
      float hn = fmaxf(y + bf2f(hb[row * DD + col]), 0.f);
      hbn[row * DD + col] = f2bf(hn);
      csum += hn;
    }
  }
  if (L == 2) {
    csum += __shfl_xor(csum, 16);
    csum += __shfl_xor(csum, 32);
    if ((lane >> 4) == 0) atomicAdd(out + nb * 16 + lane, csum);
  }
}

extern "C" void kernel_launch(void* const* d_in, const int* in_sizes, int n_in,
                              void* d_out, int out_size, void* d_ws, size_t ws_size,
                              hipStream_t stream) {
  const float* h    = (const float*)d_in[0];
  const int*   src  = (const int*)d_in[1];
  const int*   dst  = (const int*)d_in[2];
  const float* Mw   = (const float*)d_in[3];
  const float* Mb   = (const float*)d_in[4];
  const float* Uw   = (const float*)d_in[5];
  const float* Ub   = (const float*)d_in[6];
  const float* mixw = (const float*)d_in[7];
  const float* mixb = (const float*)d_in[8];
  float* out = (float*)d_out;

  hipMemsetAsync(out, 0, (size_t)out_size * sizeof(float), stream);

  k_zero<<<1563, 256, 0, stream>>>();              // zero 8 histogram replicas
  k_prephist<<<12500, 256, 0, stream>>>(h, dst);   // h prep + replicated hist + ranks
  k_scan_a<<<SCAN_BLKS, 256, 0, stream>>>();
  k_scan_b<<<1, 256, 0, stream>>>();
  k_scan_c<<<SCAN_BLKS, 256, 0, stream>>>();
  k_scatter<<<3125, 256, 0, stream>>>(src, dst);   // atomic-free CSR fill
  k_weights<<<624, 256, 0, stream>>>(Uw, mixw, Mw, Ub, mixb);

  for (int L = 0; L < NL; ++L) {
    int par = L & 1;
    k_pre<<<UPD_BLKS, 256, 0, stream>>>(Mb, L, par);
    k_aggf<<<6250, 256, 0, stream>>>();            // 8 nodes per block (2 per wave)
    k_update<<<UPD_BLKS, 256, 0, stream>>>(L, par, out);
  }
}